// Round 6
// baseline (2453.169 us; speedup 1.0000x reference)
//
#include <hip/hip_runtime.h>

// Problem constants
#define H_    128
#define W_    128
#define C_    3
#define PAD_  10
#define LWID  117          // LW = LH = 117
#define L_    13689        // LH*LW
#define LPAD  13696        // 107 * 128
#define D_    3072         // C*KH*KW
#define NMEM_ 4096

#define T_MARGIN 3.0f      // candidate margin; i8-quant score err sigma ~0.32 (9 sigma)
#define CAP_     256       // per-row candidate list capacity (expected ~70)
#define SCAP_    64        // rescue shortlist capacity (expected ~1.4)

#define PSCALE 127.0f      // patch quant scale (p in [0,1))
#define MSCALE 32.0f       // mem quant scale (clip +-3.97)
#define INVS   (1.0f / (PSCALE * MSCALE))

typedef int   intx4  __attribute__((ext_vector_type(4)));
typedef float floatx4 __attribute__((ext_vector_type(4)));

// Static device-side scratch (bss) — no d_ws dependency
__device__ int                g_best[L_];
__device__ float              g_bias[NMEM_];
__device__ unsigned           g_max;
__device__ int                g_cnt[LPAD];
__device__ unsigned long long g_list[(size_t)LPAD * CAP_];   // 28 MB
__device__ char               g_A[(size_t)LPAD * D_];        // 42 MB i8 patches
__device__ char               g_B[(size_t)NMEM_ * D_];       // 12.6 MB i8 mem

__device__ __forceinline__ unsigned sortable(float f) {
    unsigned b = __float_as_uint(f);
    return (b & 0x80000000u) ? ~b : (b | 0x80000000u);
}
__device__ __forceinline__ float unsortable(unsigned u) {
    unsigned b = (u & 0x80000000u) ? (u & 0x7FFFFFFFu) : ~u;
    return __uint_as_float(b);
}
__device__ __forceinline__ unsigned long long packkey(float s, int n) {
    // max-key == max score; ties -> smaller n (jnp.argmax first-index)
    return ((unsigned long long)sortable(s) << 32) | (unsigned)(~n);
}

// async global->LDS, 16 bytes per lane (global_load_lds_dwordx4)
__device__ __forceinline__ void gl_lds16(const char* g, char* l) {
    __builtin_amdgcn_global_load_lds(
        (const __attribute__((address_space(1))) unsigned int*)(g),
        (__attribute__((address_space(3))) unsigned int*)(l), 16, 0, 0);
}

__device__ __forceinline__ int pack4(int a, int b, int c, int d) {
    return (a & 255) | ((b & 255) << 8) | ((c & 255) << 16) | ((d & 255) << 24);
}

// ---- fused prep: quantize mem + bias | build+quantize patches | zero cnts ---
__global__ __launch_bounds__(256)
void prep(const float* __restrict__ img, const float* __restrict__ mem)
{
    const int b = blockIdx.x;
    if (b < NMEM_) {
        // quantize mem row -> g_B (i8, scale 32, clip) + exact fp32 bias
        const int n = b;
        const float4* row = (const float4*)(mem + (size_t)n * D_);
        int* q8 = (int*)(g_B + (size_t)n * D_);
        float s = 0.f;
        for (int q = threadIdx.x; q < D_ / 4; q += 256) {
            float4 v = row[q];
            int q0 = __float2int_rn(fminf(fmaxf(v.x * MSCALE, -127.f), 127.f));
            int q1 = __float2int_rn(fminf(fmaxf(v.y * MSCALE, -127.f), 127.f));
            int q2 = __float2int_rn(fminf(fmaxf(v.z * MSCALE, -127.f), 127.f));
            int q3 = __float2int_rn(fminf(fmaxf(v.w * MSCALE, -127.f), 127.f));
            q8[q] = pack4(q0, q1, q2, q3);
            s = fmaf(v.x, v.x, s); s = fmaf(v.y, v.y, s);
            s = fmaf(v.z, v.z, s); s = fmaf(v.w, v.w, s);
        }
        #pragma unroll
        for (int m = 32; m >= 1; m >>= 1) s += __shfl_down(s, m, 64);
        __shared__ float red[4];
        int lane = threadIdx.x & 63, w = threadIdx.x >> 6;
        if (lane == 0) red[w] = s;
        __syncthreads();
        if (threadIdx.x == 0) g_bias[n] = -0.5f * (red[0] + red[1] + red[2] + red[3]);
    } else {
        // build + quantize one patch row -> g_A (i8, scale 127); zero its counter
        const int l = b - NMEM_;            // 0..LPAD-1 (pad rows -> zeros)
        if (threadIdx.x == 0) { g_cnt[l] = 0; if (l == 0) g_max = 0u; }
        const int py = l / LWID, px = l - (l / LWID) * LWID;
        const bool vl = l < L_;
        int* q8 = (int*)(g_A + (size_t)l * D_);
        for (int q = threadIdx.x; q < D_ / 4; q += 256) {
            int d = q * 4;
            int c = d >> 10, rem = d & 1023, kh = rem >> 5, kw0 = rem & 31;
            int qv[4] = {0, 0, 0, 0};
            if (vl) {
                int y = py + kh - PAD_;
                if ((unsigned)y < (unsigned)H_) {
                    int xb = px + kw0 - PAD_;
                    const float* ip = img + (size_t)y * (W_ * C_) + c;
                    #pragma unroll
                    for (int t = 0; t < 4; t++) {
                        int x = xb + t;
                        if ((unsigned)x < (unsigned)W_)
                            qv[t] = __float2int_rn(ip[x * C_] * PSCALE);
                    }
                }
            }
            q8[q] = pack4(qv[0], qv[1], qv[2], qv[3]);
        }
    }
}

// ---- i8 MFMA GEMM + in-register candidate extraction ------------------------
// score[l][n] = (sum qp.qm) * INVS + bias[n]; per 64-col wave group, append
// candidates >= groupmax - T to g_list[l] (groupmax <= rowmax guarantees
// containment of everything within T of the row max).
__global__ __launch_bounds__(256)
void gemm_scores()
{
    __shared__ char sA[128 * 64];   // 128 rows x BK=64 i8
    __shared__ char sB[128 * 64];
    __shared__ float biasS[128];

    const int tid = threadIdx.x;
    const int l0 = blockIdx.y * 128;
    const int n0 = blockIdx.x * 128;

    if (tid < 128) biasS[tid] = g_bias[n0 + tid];

    const int wave = tid >> 6, lane = tid & 63;
    const int wy = wave >> 1, wx = wave & 1;      // 2x2 wave grid, 64x64 each
    const int mrow = lane & 15, kgrp = lane >> 4;

    intx4 acc[4][4];
    #pragma unroll
    for (int i = 0; i < 4; i++)
        #pragma unroll
        for (int j = 0; j < 4; j++) acc[i][j] = (intx4){0, 0, 0, 0};

    // staging: 512 chunks x 16B per 8KB tile; chunk c -> row=c>>2, kc=c&3
    const int c0 = tid, c1 = tid + 256;
    const int row0 = c0 >> 2, kc0 = c0 & 3;
    const int row1 = c1 >> 2, kc1 = c1 & 3;
    const char* Ab = g_A + (size_t)l0 * D_;
    const char* Bb = g_B + (size_t)n0 * D_;

    for (int d0 = 0; d0 < D_; d0 += 64) {
        __syncthreads();
        size_t go0 = (size_t)row0 * D_ + d0 + kc0 * 16;
        size_t go1 = (size_t)row1 * D_ + d0 + kc1 * 16;
        gl_lds16(Ab + go0, &sA[c0 * 16]);
        gl_lds16(Ab + go1, &sA[c1 * 16]);
        gl_lds16(Bb + go0, &sB[c0 * 16]);
        gl_lds16(Bb + go1, &sB[c1 * 16]);
        __syncthreads();

        intx4 a[4], bfr[4];
        #pragma unroll
        for (int i = 0; i < 4; i++) {
            a[i]   = *(const intx4*)&sA[(wy * 64 + i * 16 + mrow) * 64 + kgrp * 16];
            bfr[i] = *(const intx4*)&sB[(wx * 64 + i * 16 + mrow) * 64 + kgrp * 16];
        }
        #pragma unroll
        for (int i = 0; i < 4; i++)
            #pragma unroll
            for (int j = 0; j < 4; j++)
                acc[i][j] = __builtin_amdgcn_mfma_i32_16x16x64_i8(a[i], bfr[j], acc[i][j], 0, 0, 0);
    }

    // epilogue. C/D layout: col = lane&15 (mrow), row = kgrp*4 + reg.
    #pragma unroll
    for (int i = 0; i < 4; i++) {
        #pragma unroll
        for (int r = 0; r < 4; r++) {
            const int lrow = l0 + wy * 64 + i * 16 + kgrp * 4 + r;
            float s0 = (float)acc[i][0][r] * INVS + biasS[wx * 64 + mrow];
            float bestv = s0; int bestj = 0;
            #pragma unroll
            for (int j = 1; j < 4; j++) {
                float s = (float)acc[i][j][r] * INVS + biasS[wx * 64 + j * 16 + mrow];
                if (s > bestv) { bestv = s; bestj = j; }
            }
            unsigned long long key = packkey(bestv, n0 + wx * 64 + bestj * 16 + mrow);
            // 16-lane group max (covers the 64 cols of this wave's n-range)
            #pragma unroll
            for (int m = 1; m < 16; m <<= 1) {
                unsigned long long o = __shfl_xor(key, m, 64);
                if (o > key) key = o;
            }
            float thr = unsortable((unsigned)(key >> 32)) - T_MARGIN;
            #pragma unroll
            for (int j = 0; j < 4; j++) {
                float s = (float)acc[i][j][r] * INVS + biasS[wx * 64 + j * 16 + mrow];
                if (s >= thr) {
                    int pos = atomicAdd(&g_cnt[lrow], 1);
                    if (pos < CAP_)
                        g_list[(size_t)lrow * CAP_ + pos] =
                            packkey(s, n0 + wx * 64 + j * 16 + mrow);
                }
            }
        }
    }
}

// ---- per-row shortlist + exact fp32 rescore ---------------------------------
__global__ __launch_bounds__(256)
void reduce_rescue(const float* __restrict__ img, const float* __restrict__ mem)
{
    const int l = blockIdx.x;
    const int tid = threadIdx.x;
    const int lane = tid & 63, wave = tid >> 6;

    __shared__ unsigned long long redk[4];
    __shared__ float redf[4];
    __shared__ int   scand[SCAP_];
    __shared__ int   scnt;

    if (tid == 0) scnt = 0;
    int cnt = g_cnt[l];
    bool full = cnt > CAP_;
    __syncthreads();

    if (!full) {
        int k = cnt;
        const unsigned long long* lst = g_list + (size_t)l * CAP_;
        unsigned long long mk = 0ull;
        for (int q = tid; q < k; q += 256) {
            unsigned long long e = lst[q];
            if (e > mk) mk = e;
        }
        #pragma unroll
        for (int m = 32; m >= 1; m >>= 1) {
            unsigned long long o = __shfl_xor(mk, m, 64);
            if (o > mk) mk = o;
        }
        if (lane == 0) redk[wave] = mk;
        __syncthreads();
        unsigned long long rowk = redk[0];
        #pragma unroll
        for (int w = 1; w < 4; w++) if (redk[w] > rowk) rowk = redk[w];
        float thr = unsortable((unsigned)(rowk >> 32)) - T_MARGIN;
        for (int q = tid; q < k; q += 256) {
            unsigned long long e = lst[q];
            if (unsortable((unsigned)(e >> 32)) >= thr) {
                int p = atomicAdd(&scnt, 1);
                if (p < SCAP_) scand[p] = (int)(~(unsigned)(e & 0xFFFFFFFFull));
            }
        }
    }
    __syncthreads();
    bool scanall = full || (scnt > SCAP_);
    int kk = scanall ? NMEM_ : scnt;

    // exact fp32 rescore of the shortlist (expected ~1.4 entries)
    const int py = l / LWID, px = l - (l / LWID) * LWID;
    float bestv = -3.4e38f; int bestn = 0x7FFFFFFF;
    for (int q = 0; q < kk; q++) {
        int n = scanall ? q : scand[q];
        const float* mr = mem + (size_t)n * D_;
        float s = 0.f;
        for (int d = tid; d < D_; d += 256) {
            int c = d >> 10, rem = d & 1023, kh = rem >> 5, kw = rem & 31;
            int y = py + kh - PAD_, x = px + kw - PAD_;
            float p = ((unsigned)y < (unsigned)H_ && (unsigned)x < (unsigned)W_)
                      ? img[((size_t)y * W_ + x) * C_ + c] : 0.f;
            s = fmaf(p, mr[d], s);
        }
        #pragma unroll
        for (int sh = 32; sh >= 1; sh >>= 1) s += __shfl_xor(s, sh, 64);
        if (lane == 0) redf[wave] = s;
        __syncthreads();
        float tot = redf[0] + redf[1] + redf[2] + redf[3] + g_bias[n];
        __syncthreads();   // redf reused next iteration
        if (tot > bestv || (tot == bestv && n < bestn)) { bestv = tot; bestn = n; }
    }
    if (tid == 0) g_best[l] = bestn;
}

// ---- fold: scatter mem2[mapping[ks]] straight into the cropped output -------
__global__ __launch_bounds__(256)
void fold_scatter(const int* __restrict__ mapping,
                  const float* __restrict__ mem2,
                  float* __restrict__ out)
{
    int l = (int)(((long long)blockIdx.x * 8191) % L_);   // gcd(8191, 13689)=1
    int n = g_best[l];
    int pat = mapping[n];
    const float4* row = (const float4*)(mem2 + (size_t)pat * D_);
    int py = l / LWID, px = l - (l / LWID) * LWID;
    for (int q = threadIdx.x; q < D_ / 4; q += 256) {
        int d = q * 4;
        int c = d >> 10, rem = d & 1023, kh = rem >> 5, kw0 = rem & 31;
        int y = py + kh - PAD_;
        if ((unsigned)y >= (unsigned)H_) continue;
        float4 v = row[q];
        float vv[4] = {v.x, v.y, v.z, v.w};
        int x0 = px + kw0 - PAD_;
        float* orow = out + ((size_t)y * W_) * C_ + c;
        #pragma unroll
        for (int t = 0; t < 4; t++) {
            int x = x0 + t;
            if ((unsigned)x < (unsigned)W_)
                atomicAdd(orow + x * C_, vv[t]);
        }
    }
}

// ---- global max over out ----------------------------------------------------
__global__ __launch_bounds__(256)
void maxfind(const float* __restrict__ out)
{
    int i = blockIdx.x * 256 + threadIdx.x;
    float v = (i < H_ * W_ * C_) ? out[i] : -3.4e38f;
    #pragma unroll
    for (int s = 32; s >= 1; s >>= 1) v = fmaxf(v, __shfl_xor(v, s, 64));
    if ((threadIdx.x & 63) == 0) atomicMax(&g_max, sortable(v));
}

__global__ __launch_bounds__(256)
void normalize_k(float* __restrict__ out)
{
    int i = blockIdx.x * 256 + threadIdx.x;
    if (i >= H_ * W_ * C_) return;
    float mx = unsortable(g_max);
    out[i] = out[i] / mx;
}

extern "C" void kernel_launch(void* const* d_in, const int* in_sizes, int n_in,
                              void* d_out, int out_size, void* d_ws, size_t ws_size,
                              hipStream_t stream)
{
    const float* img     = (const float*)d_in[0];   // (128,128,3)
    const float* mem     = (const float*)d_in[1];   // (4096,3072)
    const float* mem2    = (const float*)d_in[2];   // (4096,3072)
    const int*   mapping = (const int*)d_in[3];     // (4096,)
    float* out = (float*)d_out;                     // (128,128,3)

    // d_out is poisoned 0xAA before every launch — zero it (fold accumulates).
    hipMemsetAsync(d_out, 0, (size_t)out_size * sizeof(float), stream);

    prep<<<NMEM_ + LPAD, 256, 0, stream>>>(img, mem);
    gemm_scores<<<dim3(NMEM_ / 128, LPAD / 128), 256, 0, stream>>>();
    reduce_rescue<<<L_, 256, 0, stream>>>(img, mem);
    fold_scatter<<<L_, 256, 0, stream>>>(mapping, mem2, out);
    maxfind<<<(H_ * W_ * C_ + 255) / 256, 256, 0, stream>>>(out);
    normalize_k<<<(H_ * W_ * C_ + 255) / 256, 256, 0, stream>>>(out);
}

// Round 7
// 763.476 us; speedup vs baseline: 3.2132x; 3.2132x over previous
//
#include <hip/hip_runtime.h>

// Problem constants
#define H_    128
#define W_    128
#define C_    3
#define PAD_  10
#define LWID  117          // LW = LH = 117
#define L_    13689        // LH*LW
#define LPAD  13696        // 107 * 128
#define D_    3072         // C*KH*KW
#define NMEM_ 4096

#define T_MARGIN 3.0f      // candidate margin; i8-quant score err sigma ~0.32 (9 sigma)
#define CAP_     256       // per-row candidate list capacity (expected ~70)
#define SCAP_    64        // rescue shortlist capacity (expected ~1.4)

#define PSCALE 127.0f      // patch quant scale (p in [0,1))
#define MSCALE 32.0f       // mem quant scale (clip +-3.97)
#define INVS   (1.0f / (PSCALE * MSCALE))

typedef int   intx4  __attribute__((ext_vector_type(4)));
typedef float floatx4 __attribute__((ext_vector_type(4)));

// Static device-side scratch (bss) — no d_ws dependency
__device__ int                g_best[L_];
__device__ int                g_pat[L_];     // mapping[g_best[l]] resolved in rescue
__device__ float              g_bias[NMEM_];
__device__ unsigned           g_max;
__device__ int                g_cnt[LPAD];
__device__ unsigned long long g_list[(size_t)LPAD * CAP_];   // 28 MB
__device__ char               g_A[(size_t)LPAD * D_];        // 42 MB i8 patches
__device__ char               g_B[(size_t)NMEM_ * D_];       // 12.6 MB i8 mem

__device__ __forceinline__ unsigned sortable(float f) {
    unsigned b = __float_as_uint(f);
    return (b & 0x80000000u) ? ~b : (b | 0x80000000u);
}
__device__ __forceinline__ float unsortable(unsigned u) {
    unsigned b = (u & 0x80000000u) ? (u & 0x7FFFFFFFu) : ~u;
    return __uint_as_float(b);
}
__device__ __forceinline__ unsigned long long packkey(float s, int n) {
    // max-key == max score; ties -> smaller n (jnp.argmax first-index)
    return ((unsigned long long)sortable(s) << 32) | (unsigned)(~n);
}

// async global->LDS, 16 bytes per lane (global_load_lds_dwordx4)
__device__ __forceinline__ void gl_lds16(const char* g, char* l) {
    __builtin_amdgcn_global_load_lds(
        (const __attribute__((address_space(1))) unsigned int*)(g),
        (__attribute__((address_space(3))) unsigned int*)(l), 16, 0, 0);
}

__device__ __forceinline__ int pack4(int a, int b, int c, int d) {
    return (a & 255) | ((b & 255) << 8) | ((c & 255) << 16) | ((d & 255) << 24);
}

// ---- fused prep: quantize mem + bias | build+quantize patches | zero cnts ---
__global__ __launch_bounds__(256)
void prep(const float* __restrict__ img, const float* __restrict__ mem)
{
    const int b = blockIdx.x;
    if (b < NMEM_) {
        // quantize mem row -> g_B (i8, scale 32, clip) + exact fp32 bias
        const int n = b;
        const float4* row = (const float4*)(mem + (size_t)n * D_);
        int* q8 = (int*)(g_B + (size_t)n * D_);
        float s = 0.f;
        for (int q = threadIdx.x; q < D_ / 4; q += 256) {
            float4 v = row[q];
            int q0 = __float2int_rn(fminf(fmaxf(v.x * MSCALE, -127.f), 127.f));
            int q1 = __float2int_rn(fminf(fmaxf(v.y * MSCALE, -127.f), 127.f));
            int q2 = __float2int_rn(fminf(fmaxf(v.z * MSCALE, -127.f), 127.f));
            int q3 = __float2int_rn(fminf(fmaxf(v.w * MSCALE, -127.f), 127.f));
            q8[q] = pack4(q0, q1, q2, q3);
            s = fmaf(v.x, v.x, s); s = fmaf(v.y, v.y, s);
            s = fmaf(v.z, v.z, s); s = fmaf(v.w, v.w, s);
        }
        #pragma unroll
        for (int m = 32; m >= 1; m >>= 1) s += __shfl_down(s, m, 64);
        __shared__ float red[4];
        int lane = threadIdx.x & 63, w = threadIdx.x >> 6;
        if (lane == 0) red[w] = s;
        __syncthreads();
        if (threadIdx.x == 0) g_bias[n] = -0.5f * (red[0] + red[1] + red[2] + red[3]);
    } else {
        // build + quantize one patch row -> g_A (i8, scale 127); zero its counter
        const int l = b - NMEM_;            // 0..LPAD-1 (pad rows -> zeros)
        if (threadIdx.x == 0) { g_cnt[l] = 0; if (l == 0) g_max = 0u; }
        const int py = l / LWID, px = l - (l / LWID) * LWID;
        const bool vl = l < L_;
        int* q8 = (int*)(g_A + (size_t)l * D_);
        for (int q = threadIdx.x; q < D_ / 4; q += 256) {
            int d = q * 4;
            int c = d >> 10, rem = d & 1023, kh = rem >> 5, kw0 = rem & 31;
            int qv[4] = {0, 0, 0, 0};
            if (vl) {
                int y = py + kh - PAD_;
                if ((unsigned)y < (unsigned)H_) {
                    int xb = px + kw0 - PAD_;
                    const float* ip = img + (size_t)y * (W_ * C_) + c;
                    #pragma unroll
                    for (int t = 0; t < 4; t++) {
                        int x = xb + t;
                        if ((unsigned)x < (unsigned)W_)
                            qv[t] = __float2int_rn(ip[x * C_] * PSCALE);
                    }
                }
            }
            q8[q] = pack4(qv[0], qv[1], qv[2], qv[3]);
        }
    }
}

// ---- i8 MFMA GEMM + in-register candidate extraction ------------------------
__global__ __launch_bounds__(256)
void gemm_scores()
{
    __shared__ char sA[128 * 64];   // 128 rows x BK=64 i8
    __shared__ char sB[128 * 64];
    __shared__ float biasS[128];

    const int tid = threadIdx.x;
    const int l0 = blockIdx.y * 128;
    const int n0 = blockIdx.x * 128;

    if (tid < 128) biasS[tid] = g_bias[n0 + tid];

    const int wave = tid >> 6, lane = tid & 63;
    const int wy = wave >> 1, wx = wave & 1;      // 2x2 wave grid, 64x64 each
    const int mrow = lane & 15, kgrp = lane >> 4;

    intx4 acc[4][4];
    #pragma unroll
    for (int i = 0; i < 4; i++)
        #pragma unroll
        for (int j = 0; j < 4; j++) acc[i][j] = (intx4){0, 0, 0, 0};

    // staging: 512 chunks x 16B per 8KB tile; chunk c -> row=c>>2, kc=c&3
    const int c0 = tid, c1 = tid + 256;
    const int row0 = c0 >> 2, kc0 = c0 & 3;
    const int row1 = c1 >> 2, kc1 = c1 & 3;
    const char* Ab = g_A + (size_t)l0 * D_;
    const char* Bb = g_B + (size_t)n0 * D_;

    for (int d0 = 0; d0 < D_; d0 += 64) {
        __syncthreads();
        size_t go0 = (size_t)row0 * D_ + d0 + kc0 * 16;
        size_t go1 = (size_t)row1 * D_ + d0 + kc1 * 16;
        gl_lds16(Ab + go0, &sA[c0 * 16]);
        gl_lds16(Ab + go1, &sA[c1 * 16]);
        gl_lds16(Bb + go0, &sB[c0 * 16]);
        gl_lds16(Bb + go1, &sB[c1 * 16]);
        __syncthreads();

        intx4 a[4], bfr[4];
        #pragma unroll
        for (int i = 0; i < 4; i++) {
            a[i]   = *(const intx4*)&sA[(wy * 64 + i * 16 + mrow) * 64 + kgrp * 16];
            bfr[i] = *(const intx4*)&sB[(wx * 64 + i * 16 + mrow) * 64 + kgrp * 16];
        }
        #pragma unroll
        for (int i = 0; i < 4; i++)
            #pragma unroll
            for (int j = 0; j < 4; j++)
                acc[i][j] = __builtin_amdgcn_mfma_i32_16x16x64_i8(a[i], bfr[j], acc[i][j], 0, 0, 0);
    }

    // epilogue. C/D layout: col = lane&15 (mrow), row = kgrp*4 + reg.
    #pragma unroll
    for (int i = 0; i < 4; i++) {
        #pragma unroll
        for (int r = 0; r < 4; r++) {
            const int lrow = l0 + wy * 64 + i * 16 + kgrp * 4 + r;
            float s0 = (float)acc[i][0][r] * INVS + biasS[wx * 64 + mrow];
            float bestv = s0; int bestj = 0;
            #pragma unroll
            for (int j = 1; j < 4; j++) {
                float s = (float)acc[i][j][r] * INVS + biasS[wx * 64 + j * 16 + mrow];
                if (s > bestv) { bestv = s; bestj = j; }
            }
            unsigned long long key = packkey(bestv, n0 + wx * 64 + bestj * 16 + mrow);
            // 16-lane group max (covers the 64 cols of this wave's n-range)
            #pragma unroll
            for (int m = 1; m < 16; m <<= 1) {
                unsigned long long o = __shfl_xor(key, m, 64);
                if (o > key) key = o;
            }
            float thr = unsortable((unsigned)(key >> 32)) - T_MARGIN;
            #pragma unroll
            for (int j = 0; j < 4; j++) {
                float s = (float)acc[i][j][r] * INVS + biasS[wx * 64 + j * 16 + mrow];
                if (s >= thr) {
                    int pos = atomicAdd(&g_cnt[lrow], 1);
                    if (pos < CAP_)
                        g_list[(size_t)lrow * CAP_ + pos] =
                            packkey(s, n0 + wx * 64 + j * 16 + mrow);
                }
            }
        }
    }
}

// ---- per-row shortlist + exact fp32 rescore + pattern resolve ---------------
__global__ __launch_bounds__(256)
void reduce_rescue(const float* __restrict__ img, const float* __restrict__ mem,
                   const int* __restrict__ mapping)
{
    const int l = blockIdx.x;
    const int tid = threadIdx.x;
    const int lane = tid & 63, wave = tid >> 6;

    __shared__ unsigned long long redk[4];
    __shared__ float redf[4];
    __shared__ int   scand[SCAP_];
    __shared__ int   scnt;

    if (tid == 0) scnt = 0;
    int cnt = g_cnt[l];
    bool full = cnt > CAP_;
    __syncthreads();

    if (!full) {
        int k = cnt;
        const unsigned long long* lst = g_list + (size_t)l * CAP_;
        unsigned long long mk = 0ull;
        for (int q = tid; q < k; q += 256) {
            unsigned long long e = lst[q];
            if (e > mk) mk = e;
        }
        #pragma unroll
        for (int m = 32; m >= 1; m >>= 1) {
            unsigned long long o = __shfl_xor(mk, m, 64);
            if (o > mk) mk = o;
        }
        if (lane == 0) redk[wave] = mk;
        __syncthreads();
        unsigned long long rowk = redk[0];
        #pragma unroll
        for (int w = 1; w < 4; w++) if (redk[w] > rowk) rowk = redk[w];
        float thr = unsortable((unsigned)(rowk >> 32)) - T_MARGIN;
        for (int q = tid; q < k; q += 256) {
            unsigned long long e = lst[q];
            if (unsortable((unsigned)(e >> 32)) >= thr) {
                int p = atomicAdd(&scnt, 1);
                if (p < SCAP_) scand[p] = (int)(~(unsigned)(e & 0xFFFFFFFFull));
            }
        }
    }
    __syncthreads();
    bool scanall = full || (scnt > SCAP_);
    int kk = scanall ? NMEM_ : scnt;

    // exact fp32 rescore of the shortlist (expected ~1.4 entries)
    const int py = l / LWID, px = l - (l / LWID) * LWID;
    float bestv = -3.4e38f; int bestn = 0x7FFFFFFF;
    for (int q = 0; q < kk; q++) {
        int n = scanall ? q : scand[q];
        const float* mr = mem + (size_t)n * D_;
        float s = 0.f;
        for (int d = tid; d < D_; d += 256) {
            int c = d >> 10, rem = d & 1023, kh = rem >> 5, kw = rem & 31;
            int y = py + kh - PAD_, x = px + kw - PAD_;
            float p = ((unsigned)y < (unsigned)H_ && (unsigned)x < (unsigned)W_)
                      ? img[((size_t)y * W_ + x) * C_ + c] : 0.f;
            s = fmaf(p, mr[d], s);
        }
        #pragma unroll
        for (int sh = 32; sh >= 1; sh >>= 1) s += __shfl_xor(s, sh, 64);
        if (lane == 0) redf[wave] = s;
        __syncthreads();
        float tot = redf[0] + redf[1] + redf[2] + redf[3] + g_bias[n];
        __syncthreads();   // redf reused next iteration
        if (tot > bestv || (tot == bestv && n < bestn)) { bestv = tot; bestn = n; }
    }
    if (tid == 0) { g_best[l] = bestn; g_pat[l] = mapping[bestn]; }
}

// ---- gather-fold: atomic-free overlap-add -----------------------------------
// out[y][x][c] = sum over kh,kw of mem2[pat[py][px]][c*1024+kh*32+kw],
//   py = y+PAD-kh in [0,117), px = x+PAD-kw in [0,117).
// One block per (y,c); thread = x. pat ids staged in LDS. Plain store, no
// atomics (round-6 lesson: device-scope fp atomics write through to HBM).
__global__ __launch_bounds__(128)
void gather_fold(const float* __restrict__ mem2, float* __restrict__ out)
{
    const int y = blockIdx.x;
    const int c = blockIdx.y;
    const int x = threadIdx.x;

    const int py_lo = max(0, y - 21);           // kh = y+PAD-py <= 31
    const int py_hi = min(LWID - 1, y + PAD_);  // kh >= 0
    const int nrows = py_hi - py_lo + 1;        // <= 32

    __shared__ int patS[32 * LWID];             // 15 KB
    for (int i = x; i < nrows * LWID; i += 128) {
        int rr = i / LWID, cc = i - rr * LWID;
        patS[i] = g_pat[(py_lo + rr) * LWID + cc];
    }
    __syncthreads();

    float acc = 0.f;
    const int kh_lo = y + PAD_ - py_hi;
    const int kh_hi = y + PAD_ - py_lo;
    for (int kh = kh_lo; kh <= kh_hi; ++kh) {
        const int py = y + PAD_ - kh;
        const int* prow = &patS[(py - py_lo) * LWID];
        const int dbase = c * 1024 + kh * 32;
        #pragma unroll
        for (int kw = 0; kw < 32; ++kw) {
            int px = x + PAD_ - kw;
            if ((unsigned)px < (unsigned)LWID)
                acc += mem2[(size_t)prow[px] * D_ + dbase + kw];
        }
    }
    out[((size_t)y * W_ + x) * C_ + c] = acc;
}

// ---- global max over out ----------------------------------------------------
__global__ __launch_bounds__(256)
void maxfind(const float* __restrict__ out)
{
    int i = blockIdx.x * 256 + threadIdx.x;
    float v = (i < H_ * W_ * C_) ? out[i] : -3.4e38f;
    #pragma unroll
    for (int s = 32; s >= 1; s >>= 1) v = fmaxf(v, __shfl_xor(v, s, 64));
    if ((threadIdx.x & 63) == 0) atomicMax(&g_max, sortable(v));
}

__global__ __launch_bounds__(256)
void normalize_k(float* __restrict__ out)
{
    int i = blockIdx.x * 256 + threadIdx.x;
    if (i >= H_ * W_ * C_) return;
    float mx = unsortable(g_max);
    out[i] = out[i] / mx;
}

extern "C" void kernel_launch(void* const* d_in, const int* in_sizes, int n_in,
                              void* d_out, int out_size, void* d_ws, size_t ws_size,
                              hipStream_t stream)
{
    const float* img     = (const float*)d_in[0];   // (128,128,3)
    const float* mem     = (const float*)d_in[1];   // (4096,3072)
    const float* mem2    = (const float*)d_in[2];   // (4096,3072)
    const int*   mapping = (const int*)d_in[3];     // (4096,)
    float* out = (float*)d_out;                     // (128,128,3)

    prep<<<NMEM_ + LPAD, 256, 0, stream>>>(img, mem);
    gemm_scores<<<dim3(NMEM_ / 128, LPAD / 128), 256, 0, stream>>>();
    reduce_rescue<<<L_, 256, 0, stream>>>(img, mem, mapping);
    gather_fold<<<dim3(H_, C_), 128, 0, stream>>>(mem2, out);
    maxfind<<<(H_ * W_ * C_ + 255) / 256, 256, 0, stream>>>(out);
    normalize_k<<<(H_ * W_ * C_ + 255) / 256, 256, 0, stream>>>(out);
}

// Round 8
// 695.110 us; speedup vs baseline: 3.5292x; 1.0984x over previous
//
#include <hip/hip_runtime.h>

// Problem constants
#define H_    128
#define W_    128
#define C_    3
#define PAD_  10
#define LWID  117          // LW = LH = 117
#define L_    13689        // LH*LW
#define LPAD  13696        // 107 * 128
#define D_    3072         // C*KH*KW
#define NMEM_ 4096

#define T_MARGIN 3.0f      // candidate margin; i8-quant score err sigma ~0.32 (9 sigma)
#define CAP_     256       // per-row candidate list capacity (expected ~70)
#define SCAP_    64        // rescue shortlist capacity (expected ~1.4)

#define PSCALE 127.0f      // patch quant scale (p in [0,1))
#define MSCALE 32.0f       // mem quant scale (clip +-3.97)
#define INVS   (1.0f / (PSCALE * MSCALE))

typedef int   intx4  __attribute__((ext_vector_type(4)));

// Static device-side scratch (bss) — no d_ws dependency
__device__ int                g_best[L_];
__device__ int                g_pat[L_];     // mapping[g_best[l]] resolved in rescue
__device__ float              g_bias[NMEM_];
__device__ unsigned           g_max;
__device__ int                g_cnt[LPAD];
__device__ unsigned long long g_list[(size_t)LPAD * CAP_];   // 28 MB
__device__ char               g_A[(size_t)LPAD * D_];        // 42 MB i8 patches
__device__ char               g_B[(size_t)NMEM_ * D_];       // 12.6 MB i8 mem
__device__ float              g_part[4][H_ * W_ * C_];       // fold partials, 786 KB

__device__ __forceinline__ unsigned sortable(float f) {
    unsigned b = __float_as_uint(f);
    return (b & 0x80000000u) ? ~b : (b | 0x80000000u);
}
__device__ __forceinline__ float unsortable(unsigned u) {
    unsigned b = (u & 0x80000000u) ? (u & 0x7FFFFFFFu) : ~u;
    return __uint_as_float(b);
}
__device__ __forceinline__ unsigned long long packkey(float s, int n) {
    // max-key == max score; ties -> smaller n (jnp.argmax first-index)
    return ((unsigned long long)sortable(s) << 32) | (unsigned)(~n);
}

// async global->LDS, 16 bytes per lane (global_load_lds_dwordx4)
__device__ __forceinline__ void gl_lds16(const char* g, char* l) {
    __builtin_amdgcn_global_load_lds(
        (const __attribute__((address_space(1))) unsigned int*)(g),
        (__attribute__((address_space(3))) unsigned int*)(l), 16, 0, 0);
}

__device__ __forceinline__ int pack4(int a, int b, int c, int d) {
    return (a & 255) | ((b & 255) << 8) | ((c & 255) << 16) | ((d & 255) << 24);
}

// ---- fused prep: quantize mem + bias | build+quantize patches | zero cnts ---
__global__ __launch_bounds__(256)
void prep(const float* __restrict__ img, const float* __restrict__ mem)
{
    const int b = blockIdx.x;
    if (b < NMEM_) {
        const int n = b;
        const float4* row = (const float4*)(mem + (size_t)n * D_);
        int* q8 = (int*)(g_B + (size_t)n * D_);
        float s = 0.f;
        for (int q = threadIdx.x; q < D_ / 4; q += 256) {
            float4 v = row[q];
            int q0 = __float2int_rn(fminf(fmaxf(v.x * MSCALE, -127.f), 127.f));
            int q1 = __float2int_rn(fminf(fmaxf(v.y * MSCALE, -127.f), 127.f));
            int q2 = __float2int_rn(fminf(fmaxf(v.z * MSCALE, -127.f), 127.f));
            int q3 = __float2int_rn(fminf(fmaxf(v.w * MSCALE, -127.f), 127.f));
            q8[q] = pack4(q0, q1, q2, q3);
            s = fmaf(v.x, v.x, s); s = fmaf(v.y, v.y, s);
            s = fmaf(v.z, v.z, s); s = fmaf(v.w, v.w, s);
        }
        #pragma unroll
        for (int m = 32; m >= 1; m >>= 1) s += __shfl_down(s, m, 64);
        __shared__ float red[4];
        int lane = threadIdx.x & 63, w = threadIdx.x >> 6;
        if (lane == 0) red[w] = s;
        __syncthreads();
        if (threadIdx.x == 0) g_bias[n] = -0.5f * (red[0] + red[1] + red[2] + red[3]);
    } else {
        const int l = b - NMEM_;            // 0..LPAD-1 (pad rows -> zeros)
        if (threadIdx.x == 0) { g_cnt[l] = 0; if (l == 0) g_max = 0u; }
        const int py = l / LWID, px = l - (l / LWID) * LWID;
        const bool vl = l < L_;
        int* q8 = (int*)(g_A + (size_t)l * D_);
        for (int q = threadIdx.x; q < D_ / 4; q += 256) {
            int d = q * 4;
            int c = d >> 10, rem = d & 1023, kh = rem >> 5, kw0 = rem & 31;
            int qv[4] = {0, 0, 0, 0};
            if (vl) {
                int y = py + kh - PAD_;
                if ((unsigned)y < (unsigned)H_) {
                    int xb = px + kw0 - PAD_;
                    const float* ip = img + (size_t)y * (W_ * C_) + c;
                    #pragma unroll
                    for (int t = 0; t < 4; t++) {
                        int x = xb + t;
                        if ((unsigned)x < (unsigned)W_)
                            qv[t] = __float2int_rn(ip[x * C_] * PSCALE);
                    }
                }
            }
            q8[q] = pack4(qv[0], qv[1], qv[2], qv[3]);
        }
    }
}

// ---- i8 MFMA GEMM, BK=128, XOR-swizzled LDS, XCD-aware block mapping --------
// Block decode: XCD = b&7 gets n-tiles {4*(b&7)..+3} -> per-XCD B slice 1.6 MB
// (L2-resident; g_B is 12.6 MB and would miss a 4 MB per-XCD L2 otherwise).
__global__ __launch_bounds__(256)
void gemm_scores()
{
    __shared__ char sA[128 * 128];   // 16 KB
    __shared__ char sB[128 * 128];   // 16 KB
    __shared__ float biasS[128];

    const int tid = threadIdx.x;
    const int b = blockIdx.x;
    const int nt = (b & 7) * 4 + ((b >> 3) & 3);   // 0..31
    const int lt = b >> 5;                          // 0..106
    const int l0 = lt * 128;
    const int n0 = nt * 128;

    if (tid < 128) biasS[tid] = g_bias[n0 + tid];

    const int wave = tid >> 6, lane = tid & 63;
    const int wy = wave >> 1, wx = wave & 1;      // 2x2 wave grid, 64x64 each
    const int mrow = lane & 15, kgrp = lane >> 4;

    intx4 acc[4][4];
    #pragma unroll
    for (int i = 0; i < 4; i++)
        #pragma unroll
        for (int j = 0; j < 4; j++) acc[i][j] = (intx4){0, 0, 0, 0};

    const char* Ab = g_A + (size_t)l0 * D_;
    const char* Bb = g_B + (size_t)n0 * D_;

    // Staging: 1024 16B-chunks per 16KB tile. Chunk c -> row=c>>3,
    // data sub-block jj = (c&7) ^ (row&7)  (XOR swizzle: without it, all 16
    // fragment rows read the same 4 banks -> 16-way conflict).
    for (int d0 = 0; d0 < D_; d0 += 128) {
        __syncthreads();
        #pragma unroll
        for (int t = 0; t < 4; t++) {
            int c = tid + 256 * t;
            int row = c >> 3;
            int jj = (c & 7) ^ (row & 7);
            size_t go = (size_t)row * D_ + d0 + jj * 16;
            gl_lds16(Ab + go, &sA[c * 16]);
            gl_lds16(Bb + go, &sB[c * 16]);
        }
        __syncthreads();

        #pragma unroll
        for (int ks = 0; ks < 2; ks++) {
            intx4 a[4], bf[4];
            #pragma unroll
            for (int i = 0; i < 4; i++) {
                int ra = wy * 64 + i * 16 + mrow;
                int ca = ra * 8 + ((ks * 4 + kgrp) ^ (ra & 7));
                a[i] = *(const intx4*)&sA[ca * 16];
                int rb = wx * 64 + i * 16 + mrow;
                int cb = rb * 8 + ((ks * 4 + kgrp) ^ (rb & 7));
                bf[i] = *(const intx4*)&sB[cb * 16];
            }
            #pragma unroll
            for (int i = 0; i < 4; i++)
                #pragma unroll
                for (int j = 0; j < 4; j++)
                    acc[i][j] = __builtin_amdgcn_mfma_i32_16x16x64_i8(a[i], bf[j], acc[i][j], 0, 0, 0);
        }
    }

    // epilogue. C/D layout: col = lane&15 (mrow), row = kgrp*4 + reg.
    #pragma unroll
    for (int i = 0; i < 4; i++) {
        #pragma unroll
        for (int r = 0; r < 4; r++) {
            const int lrow = l0 + wy * 64 + i * 16 + kgrp * 4 + r;
            float s0 = (float)acc[i][0][r] * INVS + biasS[wx * 64 + mrow];
            float bestv = s0; int bestj = 0;
            #pragma unroll
            for (int j = 1; j < 4; j++) {
                float s = (float)acc[i][j][r] * INVS + biasS[wx * 64 + j * 16 + mrow];
                if (s > bestv) { bestv = s; bestj = j; }
            }
            unsigned long long key = packkey(bestv, n0 + wx * 64 + bestj * 16 + mrow);
            #pragma unroll
            for (int m = 1; m < 16; m <<= 1) {
                unsigned long long o = __shfl_xor(key, m, 64);
                if (o > key) key = o;
            }
            float thr = unsortable((unsigned)(key >> 32)) - T_MARGIN;
            #pragma unroll
            for (int j = 0; j < 4; j++) {
                float s = (float)acc[i][j][r] * INVS + biasS[wx * 64 + j * 16 + mrow];
                if (s >= thr) {
                    int pos = atomicAdd(&g_cnt[lrow], 1);
                    if (pos < CAP_)
                        g_list[(size_t)lrow * CAP_ + pos] =
                            packkey(s, n0 + wx * 64 + j * 16 + mrow);
                }
            }
        }
    }
}

// ---- per-row shortlist + exact fp32 rescore + pattern resolve ---------------
__global__ __launch_bounds__(256)
void reduce_rescue(const float* __restrict__ img, const float* __restrict__ mem,
                   const int* __restrict__ mapping)
{
    const int l = blockIdx.x;
    const int tid = threadIdx.x;
    const int lane = tid & 63, wave = tid >> 6;

    __shared__ unsigned long long redk[4];
    __shared__ float redf[4];
    __shared__ int   scand[SCAP_];
    __shared__ int   scnt;

    if (tid == 0) scnt = 0;
    int cnt = g_cnt[l];
    bool full = cnt > CAP_;
    __syncthreads();

    if (!full) {
        int k = cnt;
        const unsigned long long* lst = g_list + (size_t)l * CAP_;
        unsigned long long mk = 0ull;
        for (int q = tid; q < k; q += 256) {
            unsigned long long e = lst[q];
            if (e > mk) mk = e;
        }
        #pragma unroll
        for (int m = 32; m >= 1; m >>= 1) {
            unsigned long long o = __shfl_xor(mk, m, 64);
            if (o > mk) mk = o;
        }
        if (lane == 0) redk[wave] = mk;
        __syncthreads();
        unsigned long long rowk = redk[0];
        #pragma unroll
        for (int w = 1; w < 4; w++) if (redk[w] > rowk) rowk = redk[w];
        float thr = unsortable((unsigned)(rowk >> 32)) - T_MARGIN;
        for (int q = tid; q < k; q += 256) {
            unsigned long long e = lst[q];
            if (unsortable((unsigned)(e >> 32)) >= thr) {
                int p = atomicAdd(&scnt, 1);
                if (p < SCAP_) scand[p] = (int)(~(unsigned)(e & 0xFFFFFFFFull));
            }
        }
    }
    __syncthreads();
    bool scanall = full || (scnt > SCAP_);
    int kk = scanall ? NMEM_ : scnt;

    const int py = l / LWID, px = l - (l / LWID) * LWID;
    float bestv = -3.4e38f; int bestn = 0x7FFFFFFF;
    for (int q = 0; q < kk; q++) {
        int n = scanall ? q : scand[q];
        const float* mr = mem + (size_t)n * D_;
        float s = 0.f;
        for (int d = tid; d < D_; d += 256) {
            int c = d >> 10, rem = d & 1023, kh = rem >> 5, kw = rem & 31;
            int y = py + kh - PAD_, x = px + kw - PAD_;
            float p = ((unsigned)y < (unsigned)H_ && (unsigned)x < (unsigned)W_)
                      ? img[((size_t)y * W_ + x) * C_ + c] : 0.f;
            s = fmaf(p, mr[d], s);
        }
        #pragma unroll
        for (int sh = 32; sh >= 1; sh >>= 1) s += __shfl_xor(s, sh, 64);
        if (lane == 0) redf[wave] = s;
        __syncthreads();
        float tot = redf[0] + redf[1] + redf[2] + redf[3] + g_bias[n];
        __syncthreads();   // redf reused next iteration
        if (tot > bestv || (tot == bestv && n < bestn)) { bestv = tot; bestn = n; }
    }
    if (tid == 0) { g_best[l] = bestn; g_pat[l] = mapping[bestn]; }
}

// ---- gather-fold: coalesced, py-quartered for parallelism -------------------
// Block (y, c, q). Wave-uniform patch column s => the <=32 active lanes read
// 32 CONSECUTIVE floats of one mem2 row (coalesced), vs round-7's per-lane
// scattered rows. Partials summed in maxfind.
__global__ __launch_bounds__(128)
void gather_fold(const float* __restrict__ mem2)
{
    const int y = blockIdx.x;
    const int c = blockIdx.y;
    const int q = blockIdx.z;
    const int x = threadIdx.x;            // 0..127
    const int wv = x >> 6;

    const int py_lo = max(0, y - 21);
    const int py_hi = min(LWID - 1, y + PAD_);
    const int p0 = py_lo + q * 8;
    const int p1 = min(p0 + 8, py_hi + 1);
    const int nrows = (p1 > p0) ? (p1 - p0) : 0;

    __shared__ int patS[8 * LWID];
    for (int i = x; i < nrows * LWID; i += 128) {
        int rr = i / LWID, cc = i - rr * LWID;
        patS[i] = g_pat[(p0 + rr) * LWID + cc];
    }
    __syncthreads();

    // wave 0 serves x 0..63 (s 0..73); wave 1 serves x 64..127 (s 43..116)
    const int slo = wv ? 43 : 0;
    const int shi = wv ? 116 : 73;

    float acc = 0.f;
    for (int py = p0; py < p1; ++py) {
        const int kh = y + PAD_ - py;                 // 0..31
        const int dbase = c * 1024 + kh * 32;
        const int* prow = &patS[(py - p0) * LWID];
        for (int s = slo; s <= shi; ++s) {
            int d = x + PAD_ - s;                     // lane-linear
            if ((unsigned)d < 32u)
                acc += mem2[(size_t)prow[s] * D_ + dbase + d];
        }
    }
    g_part[q][((size_t)y * W_ + x) * C_ + c] = acc;
}

// ---- sum partials + global max ----------------------------------------------
__global__ __launch_bounds__(256)
void maxfind(float* __restrict__ out)
{
    int i = blockIdx.x * 256 + threadIdx.x;           // 192*256 == 49152 exact
    float v = g_part[0][i] + g_part[1][i] + g_part[2][i] + g_part[3][i];
    out[i] = v;
    float m = v;
    #pragma unroll
    for (int s = 32; s >= 1; s >>= 1) m = fmaxf(m, __shfl_xor(m, s, 64));
    if ((threadIdx.x & 63) == 0) atomicMax(&g_max, sortable(m));
}

__global__ __launch_bounds__(256)
void normalize_k(float* __restrict__ out)
{
    int i = blockIdx.x * 256 + threadIdx.x;
    float mx = unsortable(g_max);
    out[i] = out[i] / mx;
}

extern "C" void kernel_launch(void* const* d_in, const int* in_sizes, int n_in,
                              void* d_out, int out_size, void* d_ws, size_t ws_size,
                              hipStream_t stream)
{
    const float* img     = (const float*)d_in[0];   // (128,128,3)
    const float* mem     = (const float*)d_in[1];   // (4096,3072)
    const float* mem2    = (const float*)d_in[2];   // (4096,3072)
    const int*   mapping = (const int*)d_in[3];     // (4096,)
    float* out = (float*)d_out;                     // (128,128,3)

    prep<<<NMEM_ + LPAD, 256, 0, stream>>>(img, mem);
    gemm_scores<<<(NMEM_ / 128) * (LPAD / 128), 256, 0, stream>>>();
    reduce_rescue<<<L_, 256, 0, stream>>>(img, mem, mapping);
    gather_fold<<<dim3(H_, C_, 4), 128, 0, stream>>>(mem2);
    maxfind<<<192, 256, 0, stream>>>(out);
    normalize_k<<<192, 256, 0, stream>>>(out);
}

// Round 9
// 584.231 us; speedup vs baseline: 4.1990x; 1.1898x over previous
//
#include <hip/hip_runtime.h>

// Problem constants
#define H_    128
#define W_    128
#define C_    3
#define PAD_  10
#define LWID  117          // LW = LH = 117
#define L_    13689        // LH*LW
#define LPAD  13696        // 107 * 128
#define D_    3072         // C*KH*KW
#define NMEM_ 4096

#define T_MARGIN 3.0f      // candidate margin; i8-quant score err sigma ~0.32 (9 sigma)
#define CAP_     256       // per-row candidate list capacity (expected ~70)
#define SCAP_    64        // rescue shortlist capacity (expected ~1.4)

#define PSCALE 127.0f      // patch quant scale (p in [0,1))
#define MSCALE 32.0f       // mem quant scale (clip +-3.97)
#define INVS   (1.0f / (PSCALE * MSCALE))

typedef int   intx4  __attribute__((ext_vector_type(4)));

// Static device-side scratch (bss) — no d_ws dependency
__device__ int                g_best[L_];
__device__ int                g_pat[L_];     // mapping[g_best[l]] resolved in rescue
__device__ float              g_bias[NMEM_];
__device__ unsigned           g_max;
__device__ int                g_cnt[LPAD];
__device__ unsigned long long g_list[(size_t)LPAD * CAP_];   // 28 MB
__device__ char               g_A[(size_t)LPAD * D_];        // 42 MB i8 patches
__device__ char               g_B[(size_t)NMEM_ * D_];       // 12.6 MB i8 mem
__device__ float              g_part[4][H_ * W_ * C_];       // fold partials, 786 KB

__device__ __forceinline__ unsigned sortable(float f) {
    unsigned b = __float_as_uint(f);
    return (b & 0x80000000u) ? ~b : (b | 0x80000000u);
}
__device__ __forceinline__ float unsortable(unsigned u) {
    unsigned b = (u & 0x80000000u) ? (u & 0x7FFFFFFFu) : ~u;
    return __uint_as_float(b);
}
__device__ __forceinline__ unsigned long long packkey(float s, int n) {
    // max-key == max score; ties -> smaller n (jnp.argmax first-index)
    return ((unsigned long long)sortable(s) << 32) | (unsigned)(~n);
}

// async global->LDS, 16 bytes per lane (global_load_lds_dwordx4)
__device__ __forceinline__ void gl_lds16(const char* g, char* l) {
    __builtin_amdgcn_global_load_lds(
        (const __attribute__((address_space(1))) unsigned int*)(g),
        (__attribute__((address_space(3))) unsigned int*)(l), 16, 0, 0);
}

__device__ __forceinline__ int pack4(int a, int b, int c, int d) {
    return (a & 255) | ((b & 255) << 8) | ((c & 255) << 16) | ((d & 255) << 24);
}

// ---- fused prep: quantize mem + bias | build+quantize patches | zero cnts ---
__global__ __launch_bounds__(256)
void prep(const float* __restrict__ img, const float* __restrict__ mem)
{
    const int b = blockIdx.x;
    if (b < NMEM_) {
        const int n = b;
        const float4* row = (const float4*)(mem + (size_t)n * D_);
        int* q8 = (int*)(g_B + (size_t)n * D_);
        float s = 0.f;
        for (int q = threadIdx.x; q < D_ / 4; q += 256) {
            float4 v = row[q];
            int q0 = __float2int_rn(fminf(fmaxf(v.x * MSCALE, -127.f), 127.f));
            int q1 = __float2int_rn(fminf(fmaxf(v.y * MSCALE, -127.f), 127.f));
            int q2 = __float2int_rn(fminf(fmaxf(v.z * MSCALE, -127.f), 127.f));
            int q3 = __float2int_rn(fminf(fmaxf(v.w * MSCALE, -127.f), 127.f));
            q8[q] = pack4(q0, q1, q2, q3);
            s = fmaf(v.x, v.x, s); s = fmaf(v.y, v.y, s);
            s = fmaf(v.z, v.z, s); s = fmaf(v.w, v.w, s);
        }
        #pragma unroll
        for (int m = 32; m >= 1; m >>= 1) s += __shfl_down(s, m, 64);
        __shared__ float red[4];
        int lane = threadIdx.x & 63, w = threadIdx.x >> 6;
        if (lane == 0) red[w] = s;
        __syncthreads();
        if (threadIdx.x == 0) g_bias[n] = -0.5f * (red[0] + red[1] + red[2] + red[3]);
    } else {
        const int l = b - NMEM_;            // 0..LPAD-1 (pad rows -> zeros)
        if (threadIdx.x == 0) { g_cnt[l] = 0; if (l == 0) g_max = 0u; }
        const int py = l / LWID, px = l - (l / LWID) * LWID;
        const bool vl = l < L_;
        int* q8 = (int*)(g_A + (size_t)l * D_);
        for (int q = threadIdx.x; q < D_ / 4; q += 256) {
            int d = q * 4;
            int c = d >> 10, rem = d & 1023, kh = rem >> 5, kw0 = rem & 31;
            int qv[4] = {0, 0, 0, 0};
            if (vl) {
                int y = py + kh - PAD_;
                if ((unsigned)y < (unsigned)H_) {
                    int xb = px + kw0 - PAD_;
                    const float* ip = img + (size_t)y * (W_ * C_) + c;
                    #pragma unroll
                    for (int t = 0; t < 4; t++) {
                        int x = xb + t;
                        if ((unsigned)x < (unsigned)W_)
                            qv[t] = __float2int_rn(ip[x * C_] * PSCALE);
                    }
                }
            }
            q8[q] = pack4(qv[0], qv[1], qv[2], qv[3]);
        }
    }
}

// ---- i8 MFMA GEMM, 128l x 256n tile, BK=128, XOR-swizzled LDS ---------------
// Doubled n-tile: 64 MFMA per wave per barrier pair (vs 32) to amortize the
// structural vmcnt(0) barrier drain (round-8 post-mortem: latency-bound at
// MfmaUtil 18%, nothing saturated). XCD decode: b&7 -> n-tile pair, per-XCD
// B slice 1.57 MB (L2-resident).
__global__ __launch_bounds__(256, 2)
void gemm_scores()
{
    __shared__ char sA[128 * 128];   // 16 KB
    __shared__ char sB[256 * 128];   // 32 KB
    __shared__ float biasS[256];

    const int tid = threadIdx.x;
    const int b = blockIdx.x;
    const int nt = (b & 7) * 2 + ((b >> 3) & 1);   // 0..15
    const int lt = b >> 4;                          // 0..106
    const int l0 = lt * 128;
    const int n0 = nt * 256;

    biasS[tid] = g_bias[n0 + tid];

    const int wave = tid >> 6, lane = tid & 63;
    const int wy = wave >> 1, wx = wave & 1;      // wave tile: 64l x 128n
    const int mrow = lane & 15, kgrp = lane >> 4;

    intx4 acc[4][8];
    #pragma unroll
    for (int i = 0; i < 4; i++)
        #pragma unroll
        for (int j = 0; j < 8; j++) acc[i][j] = (intx4){0, 0, 0, 0};

    const char* Ab = g_A + (size_t)l0 * D_;
    const char* Bb = g_B + (size_t)n0 * D_;

    // Staging: A 1024 + B 2048 16B-chunks per iter. Chunk c -> row=c>>3,
    // sub-block jj=(c&7)^(row&7) (XOR swizzle; round-8: conflicts -> 0).
    for (int d0 = 0; d0 < D_; d0 += 128) {
        __syncthreads();
        #pragma unroll
        for (int t = 0; t < 4; t++) {
            int c = tid + 256 * t;
            int row = c >> 3;
            int jj = (c & 7) ^ (row & 7);
            gl_lds16(Ab + (size_t)row * D_ + d0 + jj * 16, &sA[c * 16]);
        }
        #pragma unroll
        for (int t = 0; t < 8; t++) {
            int c = tid + 256 * t;
            int row = c >> 3;
            int jj = (c & 7) ^ (row & 7);
            gl_lds16(Bb + (size_t)row * D_ + d0 + jj * 16, &sB[c * 16]);
        }
        __syncthreads();

        #pragma unroll
        for (int ks = 0; ks < 2; ks++) {
            intx4 a[4], bf[8];
            #pragma unroll
            for (int i = 0; i < 4; i++) {
                int ra = wy * 64 + i * 16 + mrow;
                int ca = ra * 8 + ((ks * 4 + kgrp) ^ (ra & 7));
                a[i] = *(const intx4*)&sA[ca * 16];
            }
            #pragma unroll
            for (int j = 0; j < 8; j++) {
                int rb = wx * 128 + j * 16 + mrow;
                int cb = rb * 8 + ((ks * 4 + kgrp) ^ (rb & 7));
                bf[j] = *(const intx4*)&sB[cb * 16];
            }
            #pragma unroll
            for (int i = 0; i < 4; i++)
                #pragma unroll
                for (int j = 0; j < 8; j++)
                    acc[i][j] = __builtin_amdgcn_mfma_i32_16x16x64_i8(a[i], bf[j], acc[i][j], 0, 0, 0);
        }
    }

    // epilogue. C/D layout: col = lane&15 (mrow), row = kgrp*4 + reg.
    #pragma unroll
    for (int i = 0; i < 4; i++) {
        #pragma unroll
        for (int r = 0; r < 4; r++) {
            const int lrow = l0 + wy * 64 + i * 16 + kgrp * 4 + r;
            float sc[8];
            #pragma unroll
            for (int j = 0; j < 8; j++)
                sc[j] = (float)acc[i][j][r] * INVS + biasS[wx * 128 + j * 16 + mrow];
            float bestv = sc[0]; int bestj = 0;
            #pragma unroll
            for (int j = 1; j < 8; j++)
                if (sc[j] > bestv) { bestv = sc[j]; bestj = j; }
            unsigned long long key = packkey(bestv, n0 + wx * 128 + bestj * 16 + mrow);
            // 16-lane group max -> covers the wave's full 128-col n-range
            #pragma unroll
            for (int m = 1; m < 16; m <<= 1) {
                unsigned long long o = __shfl_xor(key, m, 64);
                if (o > key) key = o;
            }
            float thr = unsortable((unsigned)(key >> 32)) - T_MARGIN;
            #pragma unroll
            for (int j = 0; j < 8; j++) {
                if (sc[j] >= thr) {
                    int pos = atomicAdd(&g_cnt[lrow], 1);
                    if (pos < CAP_)
                        g_list[(size_t)lrow * CAP_ + pos] =
                            packkey(sc[j], n0 + wx * 128 + j * 16 + mrow);
                }
            }
        }
    }
}

// ---- per-row shortlist + exact fp32 rescore + pattern resolve ---------------
__global__ __launch_bounds__(256)
void reduce_rescue(const float* __restrict__ img, const float* __restrict__ mem,
                   const int* __restrict__ mapping)
{
    const int l = blockIdx.x;
    const int tid = threadIdx.x;
    const int lane = tid & 63, wave = tid >> 6;

    __shared__ unsigned long long redk[4];
    __shared__ float redf[4];
    __shared__ int   scand[SCAP_];
    __shared__ int   scnt;

    if (tid == 0) scnt = 0;
    int cnt = g_cnt[l];
    bool full = cnt > CAP_;
    __syncthreads();

    if (!full) {
        int k = cnt;
        const unsigned long long* lst = g_list + (size_t)l * CAP_;
        unsigned long long mk = 0ull;
        for (int q = tid; q < k; q += 256) {
            unsigned long long e = lst[q];
            if (e > mk) mk = e;
        }
        #pragma unroll
        for (int m = 32; m >= 1; m >>= 1) {
            unsigned long long o = __shfl_xor(mk, m, 64);
            if (o > mk) mk = o;
        }
        if (lane == 0) redk[wave] = mk;
        __syncthreads();
        unsigned long long rowk = redk[0];
        #pragma unroll
        for (int w = 1; w < 4; w++) if (redk[w] > rowk) rowk = redk[w];
        float thr = unsortable((unsigned)(rowk >> 32)) - T_MARGIN;
        for (int q = tid; q < k; q += 256) {
            unsigned long long e = lst[q];
            if (unsortable((unsigned)(e >> 32)) >= thr) {
                int p = atomicAdd(&scnt, 1);
                if (p < SCAP_) scand[p] = (int)(~(unsigned)(e & 0xFFFFFFFFull));
            }
        }
    }
    __syncthreads();
    bool scanall = full || (scnt > SCAP_);
    int kk = scanall ? NMEM_ : scnt;

    const int py = l / LWID, px = l - (l / LWID) * LWID;
    float bestv = -3.4e38f; int bestn = 0x7FFFFFFF;
    for (int q = 0; q < kk; q++) {
        int n = scanall ? q : scand[q];
        const float* mr = mem + (size_t)n * D_;
        float s = 0.f;
        for (int d = tid; d < D_; d += 256) {
            int c = d >> 10, rem = d & 1023, kh = rem >> 5, kw = rem & 31;
            int y = py + kh - PAD_, x = px + kw - PAD_;
            float p = ((unsigned)y < (unsigned)H_ && (unsigned)x < (unsigned)W_)
                      ? img[((size_t)y * W_ + x) * C_ + c] : 0.f;
            s = fmaf(p, mr[d], s);
        }
        #pragma unroll
        for (int sh = 32; sh >= 1; sh >>= 1) s += __shfl_xor(s, sh, 64);
        if (lane == 0) redf[wave] = s;
        __syncthreads();
        float tot = redf[0] + redf[1] + redf[2] + redf[3] + g_bias[n];
        __syncthreads();   // redf reused next iteration
        if (tot > bestv || (tot == bestv && n < bestn)) { bestv = tot; bestn = n; }
    }
    if (tid == 0) { g_best[l] = bestn; g_pat[l] = mapping[bestn]; }
}

// ---- gather-fold: coalesced, py-quartered for parallelism -------------------
__global__ __launch_bounds__(128)
void gather_fold(const float* __restrict__ mem2)
{
    const int y = blockIdx.x;
    const int c = blockIdx.y;
    const int q = blockIdx.z;
    const int x = threadIdx.x;            // 0..127
    const int wv = x >> 6;

    const int py_lo = max(0, y - 21);
    const int py_hi = min(LWID - 1, y + PAD_);
    const int p0 = py_lo + q * 8;
    const int p1 = min(p0 + 8, py_hi + 1);
    const int nrows = (p1 > p0) ? (p1 - p0) : 0;

    __shared__ int patS[8 * LWID];
    for (int i = x; i < nrows * LWID; i += 128) {
        int rr = i / LWID, cc = i - rr * LWID;
        patS[i] = g_pat[(p0 + rr) * LWID + cc];
    }
    __syncthreads();

    const int slo = wv ? 43 : 0;
    const int shi = wv ? 116 : 73;

    float acc = 0.f;
    for (int py = p0; py < p1; ++py) {
        const int kh = y + PAD_ - py;                 // 0..31
        const int dbase = c * 1024 + kh * 32;
        const int* prow = &patS[(py - p0) * LWID];
        for (int s = slo; s <= shi; ++s) {
            int d = x + PAD_ - s;                     // lane-linear
            if ((unsigned)d < 32u)
                acc += mem2[(size_t)prow[s] * D_ + dbase + d];
        }
    }
    g_part[q][((size_t)y * W_ + x) * C_ + c] = acc;
}

// ---- sum partials + global max ----------------------------------------------
__global__ __launch_bounds__(256)
void maxfind(float* __restrict__ out)
{
    int i = blockIdx.x * 256 + threadIdx.x;           // 192*256 == 49152 exact
    float v = g_part[0][i] + g_part[1][i] + g_part[2][i] + g_part[3][i];
    out[i] = v;
    float m = v;
    #pragma unroll
    for (int s = 32; s >= 1; s >>= 1) m = fmaxf(m, __shfl_xor(m, s, 64));
    if ((threadIdx.x & 63) == 0) atomicMax(&g_max, sortable(m));
}

__global__ __launch_bounds__(256)
void normalize_k(float* __restrict__ out)
{
    int i = blockIdx.x * 256 + threadIdx.x;
    float mx = unsortable(g_max);
    out[i] = out[i] / mx;
}

extern "C" void kernel_launch(void* const* d_in, const int* in_sizes, int n_in,
                              void* d_out, int out_size, void* d_ws, size_t ws_size,
                              hipStream_t stream)
{
    const float* img     = (const float*)d_in[0];   // (128,128,3)
    const float* mem     = (const float*)d_in[1];   // (4096,3072)
    const float* mem2    = (const float*)d_in[2];   // (4096,3072)
    const int*   mapping = (const int*)d_in[3];     // (4096,)
    float* out = (float*)d_out;                     // (128,128,3)

    prep<<<NMEM_ + LPAD, 256, 0, stream>>>(img, mem);
    gemm_scores<<<(NMEM_ / 256) * (LPAD / 128), 256, 0, stream>>>();
    reduce_rescue<<<L_, 256, 0, stream>>>(img, mem, mapping);
    gather_fold<<<dim3(H_, C_, 4), 128, 0, stream>>>(mem2);
    maxfind<<<192, 256, 0, stream>>>(out);
    normalize_k<<<192, 256, 0, stream>>>(out);
}